// Round 14
// baseline (105.538 us; speedup 1.0000x reference)
//
#include <hip/hip_runtime.h>
#include <stdint.h>

// CRF loss: A=8, S=200, B=64, T=32. scores (A,S,B,T,T) f32, targets (A,S,B) i32,
// mask (S,B) bool, a_mask (A,B) bool -- bool width (u8 vs i32) runtime-detected.
// R14: ASSOCIATIVE reformulation. After exp, the forward recursion is linear:
// w+^T = w^T M_s. Stage 1: one wave per (chain, 16-step segment) computes
// SEG = M_s0 ... M_s1 with MFMA 32x32x16 bf16 (f32 accum, pow2 renorm), fully
// parallel (no serial chain, no LDS, no barriers); gold-path gather fused.
// Stage 2: one wave per chain folds w0 through <=13 segment matrices (bf16 in
// d_ws) -- 13 serial steps instead of 199.
constexpr int A_ = 8, S_ = 200, B_ = 64, T_ = 32;
constexpr int START_TAG = 30, END_TAG = 31;
constexpr int SEG = 16;                    // steps per segment
constexpr int NSEG = 13;                   // ceil((S-1)/SEG)
#define LOG2E 1.44269504088896340736f
#define LN2   0.69314718055994530942f

#if __has_builtin(__builtin_amdgcn_exp2f)
#define EXP2F(x) __builtin_amdgcn_exp2f(x)
#else
#define EXP2F(x) __expf((x) * LN2)
#endif

typedef short short8 __attribute__((ext_vector_type(8)));
typedef float float16 __attribute__((ext_vector_type(16)));

__device__ __forceinline__ int load_flag(const void* p, bool u8, int idx) {
    return u8 ? (int)((const unsigned char*)p)[idx] : ((const int*)p)[idx];
}

// f32 -> bf16 bits, round-to-nearest-even (inputs are positive finite).
__device__ __forceinline__ short f2bf(float x) {
    uint32_t u = __float_as_uint(x);
    u += 0x7fffu + ((u >> 16) & 1u);
    return (short)(u >> 16);
}

__device__ __forceinline__ int first_false(const void* mask, bool u8, int b, int lane) {
    int L = S_;
    for (int base = 0; base < S_; base += 64) {
        int i = base + lane;
        int mv = (i < S_) ? load_flag(mask, u8, i * B_ + b) : 1;
        unsigned long long bal = __ballot(mv == 0);
        if (bal != 0ull && L == S_) L = base + (int)__builtin_ctzll(bal);
    }
    return L;
}

// ---------------- Stage 1: segment products via MFMA ----------------
__global__ __launch_bounds__(64)
void crf_seg_kernel(const float* __restrict__ scores,
                    const int* __restrict__ targets,
                    const void* __restrict__ mask,
                    const void* __restrict__ amask,
                    unsigned short* __restrict__ seg_ws,  // [512*13][1024] bf16 (SEG^T: [col][row])
                    float* __restrict__ c2_ws,            // [512*13] log2 scale
                    float* __restrict__ out)
{
    const int bid = blockIdx.x;            // 0 .. 512*13-1
    const int chain = bid / NSEG;
    const int seg = bid - chain * NSEG;
    const int a = chain >> 6;
    const int b = chain & (B_ - 1);
    const int lane = threadIdx.x;          // 0..63
    const int col = lane & 31;
    const int h = lane >> 5;               // half

    const bool bool_u8 = (((const int*)mask)[0] != 1);
    if (!load_flag(amask, bool_u8, chain)) return;

    const int L = first_false(mask, bool_u8, b, lane);
    const int s0 = 1 + SEG * seg;
    int len = L - s0; if (len > SEG) len = SEG;
    if (len <= 0) return;

    const size_t s_stride = (size_t)B_ * T_ * T_;       // 65536 floats
    const float* cb = scores + ((size_t)a * S_ * B_ + b) * (T_ * T_);

    // target indices for this segment (lane j holds idx of step s0+j)
    int idxv = 0;
    if (lane < len) idxv = targets[((size_t)a * S_ + s0 + lane) * B_ + b];

    // ---- init P = M_{s0+len-1} in C/D layout (coalesced row loads + exp) ----
    const float* p1 = cb + (size_t)(s0 + len - 1) * s_stride;
    float16 c;
#pragma unroll
    for (int reg = 0; reg < 16; ++reg) {
        int row = (reg & 3) + 8 * (reg >> 2) + 4 * h;
        c[reg] = EXP2F(p1[row * T_ + col] * LOG2E);
    }
    float c2 = 0.0f;
    float tga = p1[__shfl(idxv, len - 1)];  // raw gold score at step s0+len-1

#define RENORM16 do {                                                    \
        float m_ = c[0];                                                 \
        _Pragma("unroll")                                                \
        for (int i_ = 1; i_ < 16; ++i_) m_ = fmaxf(m_, c[i_]);           \
        m_ = fmaxf(m_, __shfl_xor(m_, 1));                               \
        m_ = fmaxf(m_, __shfl_xor(m_, 2));                               \
        m_ = fmaxf(m_, __shfl_xor(m_, 4));                               \
        m_ = fmaxf(m_, __shfl_xor(m_, 8));                               \
        m_ = fmaxf(m_, __shfl_xor(m_, 16));                              \
        m_ = fmaxf(m_, __shfl_xor(m_, 32));                              \
        int eb_ = (__float_as_int(m_) >> 23) & 0xff;                     \
        c2 += (float)(eb_ - 127);                                        \
        float sc_ = __int_as_float((254 - eb_) << 23);                   \
        _Pragma("unroll")                                                \
        for (int i_ = 0; i_ < 16; ++i_) c[i_] *= sc_;                    \
    } while (0)

    const float16 zf = {0,0,0,0, 0,0,0,0, 0,0,0,0, 0,0,0,0};

    // ---- descending multiply: P <- M_{s0+j} * P  (A = fresh M, B = P) ----
    for (int j = len - 2; j >= 0; --j) {
        const float* pm = cb + (size_t)(s0 + j) * s_stride;
        const float* ap = pm + col * T_ + h * 8;      // A rows: per-lane row 'col'
        float4 qa = *(const float4*)(ap);             // k = 8h+0..3
        float4 qb = *(const float4*)(ap + 4);         // k = 8h+4..7
        float4 qc = *(const float4*)(ap + 16);        // k = 16+8h+0..3
        float4 qd = *(const float4*)(ap + 20);        // k = 16+8h+4..7
        float gv = pm[__shfl(idxv, j)];               // gold gather (raw)

        short8 a1, a2;
        a1[0] = f2bf(EXP2F(qa.x * LOG2E)); a1[1] = f2bf(EXP2F(qa.y * LOG2E));
        a1[2] = f2bf(EXP2F(qa.z * LOG2E)); a1[3] = f2bf(EXP2F(qa.w * LOG2E));
        a1[4] = f2bf(EXP2F(qb.x * LOG2E)); a1[5] = f2bf(EXP2F(qb.y * LOG2E));
        a1[6] = f2bf(EXP2F(qb.z * LOG2E)); a1[7] = f2bf(EXP2F(qb.w * LOG2E));
        a2[0] = f2bf(EXP2F(qc.x * LOG2E)); a2[1] = f2bf(EXP2F(qc.y * LOG2E));
        a2[2] = f2bf(EXP2F(qc.z * LOG2E)); a2[3] = f2bf(EXP2F(qc.w * LOG2E));
        a2[4] = f2bf(EXP2F(qd.x * LOG2E)); a2[5] = f2bf(EXP2F(qd.y * LOG2E));
        a2[6] = f2bf(EXP2F(qd.z * LOG2E)); a2[7] = f2bf(EXP2F(qd.w * LOG2E));

        // B fragments of P from C/D layout: pack row-pairs to bf16 dwords,
        // swap halves via shfl_xor(32), select per half.
        uint32_t pk[8], sw[8];
#pragma unroll
        for (int p = 0; p < 8; ++p) {
            pk[p] = ((uint32_t)(uint16_t)f2bf(c[2 * p + 1]) << 16)
                  |  (uint32_t)(uint16_t)f2bf(c[2 * p]);
            sw[p] = (uint32_t)__shfl_xor((int)pk[p], 32);
        }
        union { uint32_t d[4]; short8 v; } b1u, b2u;
        b1u.d[0] = h ? sw[2] : pk[0];
        b1u.d[1] = h ? sw[3] : pk[1];
        b1u.d[2] = h ? pk[2] : sw[0];
        b1u.d[3] = h ? pk[3] : sw[1];
        b2u.d[0] = h ? sw[6] : pk[4];
        b2u.d[1] = h ? sw[7] : pk[5];
        b2u.d[2] = h ? pk[6] : sw[4];
        b2u.d[3] = h ? pk[7] : sw[5];

        float16 d = __builtin_amdgcn_mfma_f32_32x32x16_bf16(a1, b1u.v, zf, 0, 0, 0);
        d = __builtin_amdgcn_mfma_f32_32x32x16_bf16(a2, b2u.v, d, 0, 0, 0);
        c = d;
        tga += gv;
        if ((j & 3) == 0) RENORM16;
    }
    RENORM16;                               // final: max scaled into [1,2)

    // ---- store SEG^T as bf16 ([col][row], 64B rows) + c2 + gold partial ----
    unsigned short* sp = seg_ws + (size_t)bid * 1024;
    uint32_t* spd = (uint32_t*)sp;
#pragma unroll
    for (int p = 0; p < 8; ++p) {
        int rp = ((2 * p) & 3) + 8 * ((2 * p) >> 2) + 4 * h;  // row of c[2p]
        uint32_t v = ((uint32_t)(uint16_t)f2bf(c[2 * p + 1]) << 16)
                   |  (uint32_t)(uint16_t)f2bf(c[2 * p]);
        spd[col * 16 + (rp >> 1)] = v;      // bytes: col*64 + rp*2
    }
    if (lane == 0) {
        c2_ws[bid] = c2;
        atomicAdd(out, -tga * (1.0f / (float)B_));
    }
}

// ---------------- Stage 2: fold w0 through segment matrices ----------------
__global__ __launch_bounds__(64)
void crf_fold_kernel(const float* __restrict__ scores,
                     const int* __restrict__ targets,
                     const void* __restrict__ mask,
                     const void* __restrict__ amask,
                     const unsigned short* __restrict__ seg_ws,
                     const float* __restrict__ c2_ws,
                     float* __restrict__ out)
{
    const int chain = blockIdx.x;           // 0..511
    const int a = chain >> 6;
    const int b = chain & (B_ - 1);
    const int lane = threadIdx.x;
    const int t = lane & 31;
    const int fbase = (lane >> 5) << 4;     // 0 or 16

    const bool bool_u8 = (((const int*)mask)[0] != 1);
    if (!load_flag(amask, bool_u8, chain)) return;

    const int L = first_false(mask, bool_u8, b, lane);
    const float* cb = scores + ((size_t)a * S_ * B_ + b) * (T_ * T_);

    float wcur = EXP2F(cb[START_TAG * T_ + t] * LOG2E);  // all lanes hold w[t]
    float tg0 = cb[targets[(size_t)a * S_ * B_ + b]];    // gold score, step 0
    float c2 = 0.0f;

    const int nseg = (L - 1 + SEG - 1) / SEG;
    for (int seg = 0; seg < nseg; ++seg) {
        const int sid = chain * NSEG + seg;
        const unsigned short* sp = seg_ws + (size_t)sid * 1024;
        short8 u0 = *(const short8*)(sp + t * 32 + fbase);
        short8 u1 = *(const short8*)(sp + t * 32 + fbase + 8);
        float e_[16], w_[16];
#pragma unroll
        for (int i = 0; i < 8; ++i) {
            e_[i]     = __uint_as_float(((uint32_t)(uint16_t)u0[i]) << 16);
            e_[8 + i] = __uint_as_float(((uint32_t)(uint16_t)u1[i]) << 16);
        }
#pragma unroll
        for (int i = 0; i < 16; ++i)
            w_[i] = __shfl(wcur, fbase + i);
        float s0_ = fmaf(e_[3], w_[3], fmaf(e_[2], w_[2],
                    fmaf(e_[1], w_[1], e_[0] * w_[0])));
        float s1_ = fmaf(e_[7], w_[7], fmaf(e_[6], w_[6],
                    fmaf(e_[5], w_[5], e_[4] * w_[4])));
        float s2_ = fmaf(e_[11], w_[11], fmaf(e_[10], w_[10],
                    fmaf(e_[9], w_[9], e_[8] * w_[8])));
        float s3_ = fmaf(e_[15], w_[15], fmaf(e_[14], w_[14],
                    fmaf(e_[13], w_[13], e_[12] * w_[12])));
        float s_ = (s0_ + s1_) + (s2_ + s3_);
        s_ += __shfl_xor(s_, 32);            // w_new[t] on all lanes
        wcur = s_;
        c2 += c2_ws[sid];
        // per-segment power-of-2 renorm of w
        float m_ = wcur;
        m_ = fmaxf(m_, __shfl_xor(m_, 1));
        m_ = fmaxf(m_, __shfl_xor(m_, 2));
        m_ = fmaxf(m_, __shfl_xor(m_, 4));
        m_ = fmaxf(m_, __shfl_xor(m_, 8));
        m_ = fmaxf(m_, __shfl_xor(m_, 16));
        int eb_ = (__float_as_int(m_) >> 23) & 0xff;
        c2 += (float)(eb_ - 127);
        wcur *= __int_as_float((254 - eb_) << 23);
    }

    float wend = __shfl(wcur, END_TAG);
    float logZ = __logf(wend) + c2 * LN2;
    if (lane == 0)
        atomicAdd(out, (logZ - tg0) * (1.0f / (float)B_));
}

extern "C" void kernel_launch(void* const* d_in, const int* in_sizes, int n_in,
                              void* d_out, int out_size, void* d_ws, size_t ws_size,
                              hipStream_t stream) {
    const float* scores = (const float*)d_in[0];
    const int* targets  = (const int*)d_in[1];
    const void* mask    = d_in[2];
    const void* amask   = d_in[3];
    float* out = (float*)d_out;

    // ws layout: [0, 13.6MB) bf16 SEG^T matrices; then f32 c2 array.
    unsigned short* seg_ws = (unsigned short*)d_ws;
    float* c2_ws = (float*)((char*)d_ws + (size_t)(A_ * B_) * NSEG * 2048);

    hipMemsetAsync(out, 0, sizeof(float), stream);
    crf_seg_kernel<<<dim3(A_ * B_ * NSEG), dim3(64), 0, stream>>>(
        scores, targets, mask, amask, seg_ws, c2_ws, out);
    crf_fold_kernel<<<dim3(A_ * B_), dim3(64), 0, stream>>>(
        scores, targets, mask, amask, seg_ws, c2_ws, out);
}

// Round 15
// 104.590 us; speedup vs baseline: 1.0091x; 1.0091x over previous
//
#include <hip/hip_runtime.h>
#include <stdint.h>

// CRF loss: A=8, S=200, B=64, T=32. scores (A,S,B,T,T) f32, targets (A,S,B) i32,
// mask (S,B) bool, a_mask (A,B) bool -- bool width (u8 vs i32) runtime-detected.
// R15 = R14 (associative MFMA reformulation, PASSED absmax 0) + explicit 1-deep
// register prefetch in stage 1 (two named tile reg sets, unroll-by-2) so each
// wave keeps a 4KB tile in flight across the MULT -- turns the latency-serial
// loop (R14, ~105us) into a BW-bound stream. Identity-init makes all len
// multiplies uniform. Stage 2 (13-step fold) verbatim R14.
constexpr int A_ = 8, S_ = 200, B_ = 64, T_ = 32;
constexpr int START_TAG = 30, END_TAG = 31;
constexpr int SEG = 16;                    // steps per segment
constexpr int NSEG = 13;                   // ceil((S-1)/SEG)
#define LOG2E 1.44269504088896340736f
#define LN2   0.69314718055994530942f

#if __has_builtin(__builtin_amdgcn_exp2f)
#define EXP2F(x) __builtin_amdgcn_exp2f(x)
#else
#define EXP2F(x) __expf((x) * LN2)
#endif

typedef short short8 __attribute__((ext_vector_type(8)));
typedef float float16 __attribute__((ext_vector_type(16)));

__device__ __forceinline__ int load_flag(const void* p, bool u8, int idx) {
    return u8 ? (int)((const unsigned char*)p)[idx] : ((const int*)p)[idx];
}

// f32 -> bf16 bits, round-to-nearest-even (inputs are positive finite).
__device__ __forceinline__ short f2bf(float x) {
    uint32_t u = __float_as_uint(x);
    u += 0x7fffu + ((u >> 16) & 1u);
    return (short)(u >> 16);
}

__device__ __forceinline__ int first_false(const void* mask, bool u8, int b, int lane) {
    int L = S_;
    for (int base = 0; base < S_; base += 64) {
        int i = base + lane;
        int mv = (i < S_) ? load_flag(mask, u8, i * B_ + b) : 1;
        unsigned long long bal = __ballot(mv == 0);
        if (bal != 0ull && L == S_) L = base + (int)__builtin_ctzll(bal);
    }
    return L;
}

// ---------------- Stage 1: segment products via MFMA (prefetched) ----------------
__global__ __launch_bounds__(64)
void crf_seg_kernel(const float* __restrict__ scores,
                    const int* __restrict__ targets,
                    const void* __restrict__ mask,
                    const void* __restrict__ amask,
                    unsigned short* __restrict__ seg_ws,  // [512*13][1024] bf16 SEG^T
                    float* __restrict__ c2_ws,            // [512*13] log2 scale
                    float* __restrict__ out)
{
    const int bid = blockIdx.x;            // 0 .. 512*13-1
    const int chain = bid / NSEG;
    const int seg = bid - chain * NSEG;
    const int a = chain >> 6;
    const int b = chain & (B_ - 1);
    const int lane = threadIdx.x;          // 0..63
    const int col = lane & 31;
    const int h = lane >> 5;               // half

    const bool bool_u8 = (((const int*)mask)[0] != 1);
    if (!load_flag(amask, bool_u8, chain)) return;

    const int L = first_false(mask, bool_u8, b, lane);
    const int s0 = 1 + SEG * seg;
    int len = L - s0; if (len > SEG) len = SEG;
    if (len <= 0) return;

    const size_t s_stride = (size_t)B_ * T_ * T_;       // 65536 floats
    const float* cb = scores + ((size_t)a * S_ * B_ + b) * (T_ * T_);

    // target indices for this segment (lane j holds idx of step s0+j)
    int idxv = 0;
    if (lane < len) idxv = targets[((size_t)a * S_ + s0 + lane) * B_ + b];

    // ---- identity init in C/D layout: c[reg] = (row==col) ----
    float16 c;
#pragma unroll
    for (int reg = 0; reg < 16; ++reg) {
        int row = (reg & 3) + 8 * (reg >> 2) + 4 * h;
        c[reg] = (row == col) ? 1.0f : 0.0f;
    }
    float c2 = 0.0f, tga = 0.0f;

#define RENORM16 do {                                                    \
        float m_ = c[0];                                                 \
        _Pragma("unroll")                                                \
        for (int i_ = 1; i_ < 16; ++i_) m_ = fmaxf(m_, c[i_]);           \
        m_ = fmaxf(m_, __shfl_xor(m_, 1));                               \
        m_ = fmaxf(m_, __shfl_xor(m_, 2));                               \
        m_ = fmaxf(m_, __shfl_xor(m_, 4));                               \
        m_ = fmaxf(m_, __shfl_xor(m_, 8));                               \
        m_ = fmaxf(m_, __shfl_xor(m_, 16));                              \
        m_ = fmaxf(m_, __shfl_xor(m_, 32));                              \
        int eb_ = (__float_as_int(m_) >> 23) & 0xff;                     \
        c2 += (float)(eb_ - 127);                                        \
        float sc_ = __int_as_float((254 - eb_) << 23);                   \
        _Pragma("unroll")                                                \
        for (int i_ = 0; i_ < 16; ++i_) c[i_] *= sc_;                    \
    } while (0)

    const float16 zf = {0,0,0,0, 0,0,0,0, 0,0,0,0, 0,0,0,0};

    // Issue tile JJ's A-row loads (strided per-lane rows) + gold gather.
#define LOADA(QA, QB, QC, QD, G, JJ) do {                                \
        const int jj_ = (JJ);                                            \
        if (jj_ >= 0) {                                                  \
            const float* pm_ = cb + (size_t)(s0 + jj_) * s_stride;       \
            const float* ap_ = pm_ + col * T_ + h * 8;                   \
            QA = *(const float4*)(ap_);                                  \
            QB = *(const float4*)(ap_ + 4);                              \
            QC = *(const float4*)(ap_ + 16);                             \
            QD = *(const float4*)(ap_ + 20);                             \
            G  = pm_[__shfl(idxv, jj_)];                                 \
        }                                                                \
    } while (0)

    // Multiply c <- E_tile * c  (A = exp(tile) fresh, B = c rebuilt; R14-verified)
#define MULT(QA, QB, QC, QD, G) do {                                     \
        short8 a1, a2;                                                   \
        a1[0] = f2bf(EXP2F(QA.x * LOG2E)); a1[1] = f2bf(EXP2F(QA.y * LOG2E)); \
        a1[2] = f2bf(EXP2F(QA.z * LOG2E)); a1[3] = f2bf(EXP2F(QA.w * LOG2E)); \
        a1[4] = f2bf(EXP2F(QB.x * LOG2E)); a1[5] = f2bf(EXP2F(QB.y * LOG2E)); \
        a1[6] = f2bf(EXP2F(QB.z * LOG2E)); a1[7] = f2bf(EXP2F(QB.w * LOG2E)); \
        a2[0] = f2bf(EXP2F(QC.x * LOG2E)); a2[1] = f2bf(EXP2F(QC.y * LOG2E)); \
        a2[2] = f2bf(EXP2F(QC.z * LOG2E)); a2[3] = f2bf(EXP2F(QC.w * LOG2E)); \
        a2[4] = f2bf(EXP2F(QD.x * LOG2E)); a2[5] = f2bf(EXP2F(QD.y * LOG2E)); \
        a2[6] = f2bf(EXP2F(QD.z * LOG2E)); a2[7] = f2bf(EXP2F(QD.w * LOG2E)); \
        uint32_t pk[8], sw[8];                                           \
        _Pragma("unroll")                                                \
        for (int p = 0; p < 8; ++p) {                                    \
            pk[p] = ((uint32_t)(uint16_t)f2bf(c[2 * p + 1]) << 16)       \
                  |  (uint32_t)(uint16_t)f2bf(c[2 * p]);                 \
            sw[p] = (uint32_t)__shfl_xor((int)pk[p], 32);                \
        }                                                                \
        union { uint32_t d[4]; short8 v; } b1u, b2u;                     \
        b1u.d[0] = h ? sw[2] : pk[0];                                    \
        b1u.d[1] = h ? sw[3] : pk[1];                                    \
        b1u.d[2] = h ? pk[2] : sw[0];                                    \
        b1u.d[3] = h ? pk[3] : sw[1];                                    \
        b2u.d[0] = h ? sw[6] : pk[4];                                    \
        b2u.d[1] = h ? sw[7] : pk[5];                                    \
        b2u.d[2] = h ? pk[6] : sw[4];                                    \
        b2u.d[3] = h ? pk[7] : sw[5];                                    \
        float16 d_ = __builtin_amdgcn_mfma_f32_32x32x16_bf16(a1, b1u.v, zf, 0, 0, 0); \
        d_ = __builtin_amdgcn_mfma_f32_32x32x16_bf16(a2, b2u.v, d_, 0, 0, 0); \
        c = d_;                                                          \
        tga += G;                                                        \
    } while (0)

    // ---- main loop: descending j, unroll-by-2, 1-deep prefetch (X/Y sets) ----
    float4 Xa, Xb, Xc, Xd, Ya, Yb, Yc, Yd;
    float gX = 0.0f, gY = 0.0f;
    int j = len - 1;
    LOADA(Xa, Xb, Xc, Xd, gX, j);
    while (true) {
        LOADA(Ya, Yb, Yc, Yd, gY, j - 1);  // in flight across MULT(X)
        MULT(Xa, Xb, Xc, Xd, gX);
        if ((j & 3) == 0) RENORM16;
        if (--j < 0) break;
        LOADA(Xa, Xb, Xc, Xd, gX, j - 1);  // in flight across MULT(Y)
        MULT(Ya, Yb, Yc, Yd, gY);
        if ((j & 3) == 0) RENORM16;
        if (--j < 0) break;
    }
    RENORM16;                               // final: max scaled into [1,2)

    // ---- store SEG^T as bf16 ([col][row] pairs) + c2 + gold partial (R14) ----
    unsigned short* sp = seg_ws + (size_t)bid * 1024;
    uint32_t* spd = (uint32_t*)sp;
#pragma unroll
    for (int p = 0; p < 8; ++p) {
        int rp = ((2 * p) & 3) + 8 * ((2 * p) >> 2) + 4 * h;  // row of c[2p]
        uint32_t v = ((uint32_t)(uint16_t)f2bf(c[2 * p + 1]) << 16)
                   |  (uint32_t)(uint16_t)f2bf(c[2 * p]);
        spd[col * 16 + (rp >> 1)] = v;      // bytes: col*64 + rp*2
    }
    if (lane == 0) {
        c2_ws[bid] = c2;
        atomicAdd(out, -tga * (1.0f / (float)B_));
    }
}

// ---------------- Stage 2: fold w0 through segment matrices (R14, verbatim) ----------------
__global__ __launch_bounds__(64)
void crf_fold_kernel(const float* __restrict__ scores,
                     const int* __restrict__ targets,
                     const void* __restrict__ mask,
                     const void* __restrict__ amask,
                     const unsigned short* __restrict__ seg_ws,
                     const float* __restrict__ c2_ws,
                     float* __restrict__ out)
{
    const int chain = blockIdx.x;           // 0..511
    const int a = chain >> 6;
    const int b = chain & (B_ - 1);
    const int lane = threadIdx.x;
    const int t = lane & 31;
    const int fbase = (lane >> 5) << 4;     // 0 or 16

    const bool bool_u8 = (((const int*)mask)[0] != 1);
    if (!load_flag(amask, bool_u8, chain)) return;

    const int L = first_false(mask, bool_u8, b, lane);
    const float* cb = scores + ((size_t)a * S_ * B_ + b) * (T_ * T_);

    float wcur = EXP2F(cb[START_TAG * T_ + t] * LOG2E);  // all lanes hold w[t]
    float tg0 = cb[targets[(size_t)a * S_ * B_ + b]];    // gold score, step 0
    float c2 = 0.0f;

    const int nseg = (L - 1 + SEG - 1) / SEG;
    for (int seg = 0; seg < nseg; ++seg) {
        const int sid = chain * NSEG + seg;
        const unsigned short* sp = seg_ws + (size_t)sid * 1024;
        short8 u0 = *(const short8*)(sp + t * 32 + fbase);
        short8 u1 = *(const short8*)(sp + t * 32 + fbase + 8);
        float e_[16], w_[16];
#pragma unroll
        for (int i = 0; i < 8; ++i) {
            e_[i]     = __uint_as_float(((uint32_t)(uint16_t)u0[i]) << 16);
            e_[8 + i] = __uint_as_float(((uint32_t)(uint16_t)u1[i]) << 16);
        }
#pragma unroll
        for (int i = 0; i < 16; ++i)
            w_[i] = __shfl(wcur, fbase + i);
        float s0_ = fmaf(e_[3], w_[3], fmaf(e_[2], w_[2],
                    fmaf(e_[1], w_[1], e_[0] * w_[0])));
        float s1_ = fmaf(e_[7], w_[7], fmaf(e_[6], w_[6],
                    fmaf(e_[5], w_[5], e_[4] * w_[4])));
        float s2_ = fmaf(e_[11], w_[11], fmaf(e_[10], w_[10],
                    fmaf(e_[9], w_[9], e_[8] * w_[8])));
        float s3_ = fmaf(e_[15], w_[15], fmaf(e_[14], w_[14],
                    fmaf(e_[13], w_[13], e_[12] * w_[12])));
        float s_ = (s0_ + s1_) + (s2_ + s3_);
        s_ += __shfl_xor(s_, 32);            // w_new[t] on all lanes
        wcur = s_;
        c2 += c2_ws[sid];
        float m_ = wcur;
        m_ = fmaxf(m_, __shfl_xor(m_, 1));
        m_ = fmaxf(m_, __shfl_xor(m_, 2));
        m_ = fmaxf(m_, __shfl_xor(m_, 4));
        m_ = fmaxf(m_, __shfl_xor(m_, 8));
        m_ = fmaxf(m_, __shfl_xor(m_, 16));
        int eb_ = (__float_as_int(m_) >> 23) & 0xff;
        c2 += (float)(eb_ - 127);
        wcur *= __int_as_float((254 - eb_) << 23);
    }

    float wend = __shfl(wcur, END_TAG);
    float logZ = __logf(wend) + c2 * LN2;
    if (lane == 0)
        atomicAdd(out, (logZ - tg0) * (1.0f / (float)B_));
}

extern "C" void kernel_launch(void* const* d_in, const int* in_sizes, int n_in,
                              void* d_out, int out_size, void* d_ws, size_t ws_size,
                              hipStream_t stream) {
    const float* scores = (const float*)d_in[0];
    const int* targets  = (const int*)d_in[1];
    const void* mask    = d_in[2];
    const void* amask   = d_in[3];
    float* out = (float*)d_out;

    // ws layout: [0, 13.6MB) bf16 SEG^T matrices; then f32 c2 array.
    unsigned short* seg_ws = (unsigned short*)d_ws;
    float* c2_ws = (float*)((char*)d_ws + (size_t)(A_ * B_) * NSEG * 2048);

    hipMemsetAsync(out, 0, sizeof(float), stream);
    crf_seg_kernel<<<dim3(A_ * B_ * NSEG), dim3(64), 0, stream>>>(
        scores, targets, mask, amask, seg_ws, c2_ws, out);
    crf_fold_kernel<<<dim3(A_ * B_), dim3(64), 0, stream>>>(
        scores, targets, mask, amask, seg_ws, c2_ws, out);
}